// Round 1
// baseline (2016.821 us; speedup 1.0000x reference)
//
#include <hip/hip_runtime.h>
#include <hip/hip_bf16.h>
#include <cstddef>

#define B_  8
#define N_  784
#define D_  768
#define H_  16
#define HD_ 48
#define M_TOT (B_*N_)   // 6272

// ---------------------------------------------------------------------------
// Kernel 1: QKV projection GEMM.  out[row,col] = dot(x[row,:], W[col,:])
// W rows = concat(w_qk[0:1536], w_v[0:768]).  Scatter into Q/K/V [B,H,N,48].
// 64x64 tile, BK=16, 256 threads, 4x4 per thread.
// ---------------------------------------------------------------------------
__global__ __launch_bounds__(256) void qkv_gemm(
    const float* __restrict__ x,
    const float* __restrict__ w_qk,
    const float* __restrict__ w_v,
    float* __restrict__ Qo, float* __restrict__ Ko, float* __restrict__ Vo)
{
    __shared__ float As[16][68];
    __shared__ float Bs[16][68];
    const int tid = threadIdx.x;
    const int m0 = blockIdx.x * 64;
    const int n0 = blockIdx.y * 64;   // 0..2303; tiles never straddle the 1536 boundary

    const float* Wbase  = (n0 < 2*D_) ? w_qk : w_v;
    const int    colbas = (n0 < 2*D_) ? n0   : (n0 - 2*D_);

    const int lrow  = tid >> 2;        // 0..63
    const int lquad = (tid & 3) << 2;  // 0,4,8,12
    const int ty = tid >> 4, tx = tid & 15;

    float acc[4][4] = {};

    for (int k0 = 0; k0 < D_; k0 += 16) {
        float4 av = *reinterpret_cast<const float4*>(&x[(size_t)(m0 + lrow)*D_ + k0 + lquad]);
        float4 bv = *reinterpret_cast<const float4*>(&Wbase[(size_t)(colbas + lrow)*D_ + k0 + lquad]);
        __syncthreads();
        As[lquad+0][lrow] = av.x; As[lquad+1][lrow] = av.y;
        As[lquad+2][lrow] = av.z; As[lquad+3][lrow] = av.w;
        Bs[lquad+0][lrow] = bv.x; Bs[lquad+1][lrow] = bv.y;
        Bs[lquad+2][lrow] = bv.z; Bs[lquad+3][lrow] = bv.w;
        __syncthreads();
        #pragma unroll
        for (int k = 0; k < 16; ++k) {
            float4 a = *reinterpret_cast<const float4*>(&As[k][ty << 2]);
            float4 bq = *reinterpret_cast<const float4*>(&Bs[k][tx << 2]);
            float a4[4] = {a.x, a.y, a.z, a.w};
            float b4[4] = {bq.x, bq.y, bq.z, bq.w};
            #pragma unroll
            for (int i = 0; i < 4; ++i)
                #pragma unroll
                for (int j = 0; j < 4; ++j)
                    acc[i][j] += a4[i] * b4[j];
        }
    }

    #pragma unroll
    for (int i = 0; i < 4; ++i) {
        const int row = m0 + (ty << 2) + i;
        const int bb = row / N_, nn = row % N_;
        #pragma unroll
        for (int j = 0; j < 4; ++j) {
            const int col = n0 + (tx << 2) + j;
            float v = acc[i][j];
            float* dst; int c;
            if (col < D_)        { dst = Qo; c = col; }
            else if (col < 2*D_) { dst = Ko; c = col - D_; }
            else                 { dst = Vo; c = col - 2*D_; }
            dst[(((size_t)bb*H_ + c / HD_)*N_ + nn)*HD_ + (c % HD_)] = v;
        }
    }
}

// ---------------------------------------------------------------------------
// Kernel 2: fused attention for one (b, h, 16 query rows).
//  Phase A: S[16][784] = Q K^T * scale   (K staged in 56-row LDS chunks)
//  Phase B: per-row attn softmax stats + pos softmax stats (on-the-fly logits)
//  Phase C: blend (1-g)*softmax(S) + g*softmax(pos) in place   (renorm skipped:
//           row-sum is exactly 1 up to ~2e-6)
//  Phase D: Y[16][48] = S @ V   (V staged in 56-row LDS chunks)
// ---------------------------------------------------------------------------
__global__ __launch_bounds__(256) void attn_kernel(
    const float* __restrict__ Q, const float* __restrict__ K,
    const float* __restrict__ V,
    const float* __restrict__ w_pos, const float* __restrict__ b_pos,
    const float* __restrict__ gating, float* __restrict__ Y)
{
    __shared__ float Qs[16][48];     // 3.0 KB
    __shared__ float S[16][784];     // 50.2 KB
    __shared__ float KVs[56][49];    // 11.0 KB  (padded stride 49: conflict-free)

    const int tid = threadIdx.x;
    const int n0 = blockIdx.x * 16;
    const int h  = blockIdx.y;
    const int b  = blockIdx.z;
    const size_t bh = ((size_t)b*H_ + h) * N_;

    for (int idx = tid; idx < 16*HD_; idx += 256) {
        int r = idx / HD_, d = idx % HD_;
        Qs[r][d] = Q[(bh + n0 + r)*HD_ + d];
    }
    const float w0 = w_pos[h*3+0], w1 = w_pos[h*3+1], w2 = w_pos[h*3+2];
    const float bp = b_pos[h];
    const float g  = 1.f / (1.f + __expf(-gating[h]));
    const float scale = 0.14433756729740643f;  // 48^-0.5
    __syncthreads();

    // ---- Phase A: content logits ----
    for (int mc = 0; mc < N_; mc += 56) {
        for (int idx = tid; idx < 56*HD_; idx += 256) {
            int kr = idx / HD_, d = idx % HD_;
            KVs[kr][d] = K[(bh + mc + kr)*HD_ + d];
        }
        __syncthreads();
        for (int o = tid; o < 16*56; o += 256) {
            int r = o / 56, m = o % 56;
            float s = 0.f;
            #pragma unroll
            for (int j = 0; j < HD_; ++j) s += Qs[r][j] * KVs[m][j];
            S[r][mc + m] = s * scale;
        }
        __syncthreads();
    }

    // ---- Phase B: softmax statistics (16 lanes per row) ----
    const int r = tid >> 4;
    const int c = tid & 15;
    const int ng = n0 + r;
    const float nx = (float)(ng % 28), ny = (float)(ng / 28);

    float ma = -1e30f;
    for (int t = 0; t < 49; ++t) ma = fmaxf(ma, S[r][c + 16*t]);
    for (int w = 1; w < 16; w <<= 1) ma = fmaxf(ma, __shfl_xor(ma, w, 16));
    float za = 0.f;
    for (int t = 0; t < 49; ++t) za += __expf(S[r][c + 16*t] - ma);
    for (int w = 1; w < 16; w <<= 1) za += __shfl_xor(za, w, 16);

    float mp = -1e30f;
    for (int t = 0; t < 49; ++t) {
        int m = c + 16*t;
        float dx = (float)(m % 28) - nx, dy = (float)(m / 28) - ny;
        float sp = w0*dx + w1*dy + w2*(dx*dx + dy*dy) + bp;
        mp = fmaxf(mp, sp);
    }
    for (int w = 1; w < 16; w <<= 1) mp = fmaxf(mp, __shfl_xor(mp, w, 16));
    float zp = 0.f;
    for (int t = 0; t < 49; ++t) {
        int m = c + 16*t;
        float dx = (float)(m % 28) - nx, dy = (float)(m / 28) - ny;
        float sp = w0*dx + w1*dy + w2*(dx*dx + dy*dy) + bp;
        zp += __expf(sp - mp);
    }
    for (int w = 1; w < 16; w <<= 1) zp += __shfl_xor(zp, w, 16);

    // ---- Phase C: blend in place ----
    const float ia = (1.f - g) / za;
    const float ip = g / zp;
    for (int t = 0; t < 49; ++t) {
        int m = c + 16*t;
        float dx = (float)(m % 28) - nx, dy = (float)(m / 28) - ny;
        float sp = w0*dx + w1*dy + w2*(dx*dx + dy*dy) + bp;
        S[r][m] = ia * __expf(S[r][m] - ma) + ip * __expf(sp - mp);
    }

    // ---- Phase D: Y = S @ V ----
    const int dg = tid & 15;   // output d = dg*3 + {0,1,2}
    const int rr = tid >> 4;
    float acc0 = 0.f, acc1 = 0.f, acc2 = 0.f;
    for (int mc = 0; mc < N_; mc += 56) {
        __syncthreads();   // previous KVs reads done; also orders Phase C stores
        for (int idx = tid; idx < 56*HD_; idx += 256) {
            int vr = idx / HD_, d = idx % HD_;
            KVs[vr][d] = V[(bh + mc + vr)*HD_ + d];
        }
        __syncthreads();
        #pragma unroll 8
        for (int m = 0; m < 56; ++m) {
            float wgt = S[rr][mc + m];
            acc0 += wgt * KVs[m][dg*3 + 0];
            acc1 += wgt * KVs[m][dg*3 + 1];
            acc2 += wgt * KVs[m][dg*3 + 2];
        }
    }
    const size_t yo = ((size_t)b*N_ + n0 + rr)*D_ + h*HD_ + dg*3;
    Y[yo+0] = acc0; Y[yo+1] = acc1; Y[yo+2] = acc2;
}

// ---------------------------------------------------------------------------
// Kernel 3: output projection GEMM + bias.  out = Y @ w_proj^T + b_proj
// ---------------------------------------------------------------------------
__global__ __launch_bounds__(256) void proj_gemm(
    const float* __restrict__ Yi, const float* __restrict__ w_proj,
    const float* __restrict__ b_proj, float* __restrict__ out)
{
    __shared__ float As[16][68];
    __shared__ float Bs[16][68];
    const int tid = threadIdx.x;
    const int m0 = blockIdx.x * 64;
    const int n0 = blockIdx.y * 64;
    const int lrow  = tid >> 2;
    const int lquad = (tid & 3) << 2;
    const int ty = tid >> 4, tx = tid & 15;

    float acc[4][4] = {};
    for (int k0 = 0; k0 < D_; k0 += 16) {
        float4 av = *reinterpret_cast<const float4*>(&Yi[(size_t)(m0 + lrow)*D_ + k0 + lquad]);
        float4 bv = *reinterpret_cast<const float4*>(&w_proj[(size_t)(n0 + lrow)*D_ + k0 + lquad]);
        __syncthreads();
        As[lquad+0][lrow] = av.x; As[lquad+1][lrow] = av.y;
        As[lquad+2][lrow] = av.z; As[lquad+3][lrow] = av.w;
        Bs[lquad+0][lrow] = bv.x; Bs[lquad+1][lrow] = bv.y;
        Bs[lquad+2][lrow] = bv.z; Bs[lquad+3][lrow] = bv.w;
        __syncthreads();
        #pragma unroll
        for (int k = 0; k < 16; ++k) {
            float4 a = *reinterpret_cast<const float4*>(&As[k][ty << 2]);
            float4 bq = *reinterpret_cast<const float4*>(&Bs[k][tx << 2]);
            float a4[4] = {a.x, a.y, a.z, a.w};
            float b4[4] = {bq.x, bq.y, bq.z, bq.w};
            #pragma unroll
            for (int i = 0; i < 4; ++i)
                #pragma unroll
                for (int j = 0; j < 4; ++j)
                    acc[i][j] += a4[i] * b4[j];
        }
    }

    #pragma unroll
    for (int i = 0; i < 4; ++i) {
        const int row = m0 + (ty << 2) + i;
        const int col = n0 + (tx << 2);
        float4 o;
        o.x = acc[i][0] + b_proj[col+0];
        o.y = acc[i][1] + b_proj[col+1];
        o.z = acc[i][2] + b_proj[col+2];
        o.w = acc[i][3] + b_proj[col+3];
        *reinterpret_cast<float4*>(&out[(size_t)row*D_ + col]) = o;
    }
}

// ---------------------------------------------------------------------------
extern "C" void kernel_launch(void* const* d_in, const int* in_sizes, int n_in,
                              void* d_out, int out_size, void* d_ws, size_t ws_size,
                              hipStream_t stream)
{
    const float* x      = (const float*)d_in[0];
    const float* w_qk   = (const float*)d_in[1];
    const float* w_v    = (const float*)d_in[2];
    const float* w_proj = (const float*)d_in[3];
    const float* b_proj = (const float*)d_in[4];
    const float* w_pos  = (const float*)d_in[5];
    const float* b_pos  = (const float*)d_in[6];
    const float* gating = (const float*)d_in[7];
    float* out = (float*)d_out;

    const size_t per = (size_t)B_*H_*N_*HD_;   // 4,816,896 floats
    float* Q = (float*)d_ws;
    float* K = Q + per;
    float* V = K + per;
    float* Y = V + per;

    qkv_gemm<<<dim3(M_TOT/64, (3*D_)/64), 256, 0, stream>>>(x, w_qk, w_v, Q, K, V);
    attn_kernel<<<dim3(N_/16, H_, B_), 256, 0, stream>>>(Q, K, V, w_pos, b_pos, gating, Y);
    proj_gemm<<<dim3(M_TOT/64, D_/64), 256, 0, stream>>>(Y, w_proj, b_proj, out);
}

// Round 2
// 547.988 us; speedup vs baseline: 3.6804x; 3.6804x over previous
//
#include <hip/hip_runtime.h>
#include <hip/hip_bf16.h>
#include <cstddef>

#define B_  8
#define N_  784
#define D_  768
#define H_  16
#define HD_ 48
#define M_TOT (B_*N_)   // 6272

typedef __attribute__((ext_vector_type(8))) short bf8v;
typedef __attribute__((ext_vector_type(4))) short bf4v;
typedef __attribute__((ext_vector_type(4))) float f4v;

__device__ __forceinline__ short f2bf(float f) {
    __hip_bfloat16 h = __float2bfloat16(f);
    return __builtin_bit_cast(short, h);
}

// ---------------------------------------------------------------------------
// Kernel 1: QKV projection GEMM (f32 compute).  Epilogue writes bf16:
//   Qb, Kb as [B,H,N,48] bf16;  V transposed to Vt [B,H,48,N] bf16.
// ---------------------------------------------------------------------------
__global__ __launch_bounds__(256) void qkv_gemm(
    const float* __restrict__ x,
    const float* __restrict__ w_qk,
    const float* __restrict__ w_v,
    short* __restrict__ Qb, short* __restrict__ Kb, short* __restrict__ Vt)
{
    __shared__ float As[16][68];
    __shared__ float Bs[16][68];
    const int tid = threadIdx.x;
    const int m0 = blockIdx.x * 64;
    const int n0 = blockIdx.y * 64;

    const float* Wbase  = (n0 < 2*D_) ? w_qk : w_v;
    const int    colbas = (n0 < 2*D_) ? n0   : (n0 - 2*D_);

    const int lrow  = tid >> 2;
    const int lquad = (tid & 3) << 2;
    const int ty = tid >> 4, tx = tid & 15;

    float acc[4][4] = {};

    for (int k0 = 0; k0 < D_; k0 += 16) {
        float4 av = *reinterpret_cast<const float4*>(&x[(size_t)(m0 + lrow)*D_ + k0 + lquad]);
        float4 bv = *reinterpret_cast<const float4*>(&Wbase[(size_t)(colbas + lrow)*D_ + k0 + lquad]);
        __syncthreads();
        As[lquad+0][lrow] = av.x; As[lquad+1][lrow] = av.y;
        As[lquad+2][lrow] = av.z; As[lquad+3][lrow] = av.w;
        Bs[lquad+0][lrow] = bv.x; Bs[lquad+1][lrow] = bv.y;
        Bs[lquad+2][lrow] = bv.z; Bs[lquad+3][lrow] = bv.w;
        __syncthreads();
        #pragma unroll
        for (int k = 0; k < 16; ++k) {
            float4 a = *reinterpret_cast<const float4*>(&As[k][ty << 2]);
            float4 bq = *reinterpret_cast<const float4*>(&Bs[k][tx << 2]);
            float a4[4] = {a.x, a.y, a.z, a.w};
            float b4[4] = {bq.x, bq.y, bq.z, bq.w};
            #pragma unroll
            for (int i = 0; i < 4; ++i)
                #pragma unroll
                for (int j = 0; j < 4; ++j)
                    acc[i][j] += a4[i] * b4[j];
        }
    }

    #pragma unroll
    for (int i = 0; i < 4; ++i) {
        const int row = m0 + (ty << 2) + i;
        const int bb = row / N_, nn = row % N_;
        #pragma unroll
        for (int j = 0; j < 4; ++j) {
            const int col = n0 + (tx << 2) + j;
            short bv = f2bf(acc[i][j]);
            if (col < D_) {
                Qb[(((size_t)bb*H_ + col/HD_)*N_ + nn)*HD_ + (col % HD_)] = bv;
            } else if (col < 2*D_) {
                int c = col - D_;
                Kb[(((size_t)bb*H_ + c/HD_)*N_ + nn)*HD_ + (c % HD_)] = bv;
            } else {
                int c = col - 2*D_;
                Vt[(((size_t)bb*H_ + c/HD_)*HD_ + (c % HD_))*N_ + nn] = bv;
            }
        }
    }
}

// ---------------------------------------------------------------------------
// Kernel 2: MFMA flash attention, dual online softmax (content + positional).
// One wave = 16 q-rows of one (b,h). No LDS.
//   Swapped QK^T: S^T = mfma(K_chunk, Q^T) -> lane holds S[q=lane&15][key=4g+i]
//   which IS the A-operand layout of 16x16x16 MFMA for PV.
// ---------------------------------------------------------------------------
__global__ __launch_bounds__(256) void attn_mfma(
    const short* __restrict__ Qb, const short* __restrict__ Kb,
    const short* __restrict__ Vt,
    const float* __restrict__ w_pos, const float* __restrict__ b_pos,
    const float* __restrict__ gating, float* __restrict__ Y)
{
    const int lane = threadIdx.x & 63;
    const int wid  = threadIdx.x >> 6;
    const int gidx = blockIdx.x * 4 + wid;        // 0..6271
    const int qt = gidx % 49;
    const int h  = (gidx / 49) & (H_ - 1);
    const int b  = gidx / (49 * H_);
    const int c16 = lane & 15;                    // q-row | key-row | d-col
    const int g   = lane >> 4;                    // 4-lane-group id

    const size_t bh = (size_t)b*H_ + h;
    const short* Qrow  = Qb + (bh*N_ + qt*16 + c16)*HD_;
    const bf8v qf0 = *reinterpret_cast<const bf8v*>(Qrow + g*8);        // d 0..31
    const bf4v qf1 = *reinterpret_cast<const bf4v*>(Qrow + 32 + g*4);   // d 32..47

    const short* Kbase = Kb + bh*N_*HD_;
    const short* Vbase = Vt + bh*HD_*N_;

    const float w0 = w_pos[h*3+0], w1 = w_pos[h*3+1], w2 = w_pos[h*3+2];
    const float bp = b_pos[h];
    const float gate = 1.f / (1.f + __expf(-gating[h]));
    const float scale = 0.14433756729740643f;     // 48^-0.5

    const int nq = qt*16 + c16;
    const float nx = (float)(nq % 28), ny = (float)(nq / 28);

    float m_a = -1e30f, z_a = 0.f;
    float m_p = -1e30f, z_p = 0.f;
    f4v acc_a0 = {0.f,0.f,0.f,0.f}, acc_a1 = {0.f,0.f,0.f,0.f}, acc_a2 = {0.f,0.f,0.f,0.f};
    f4v acc_p0 = {0.f,0.f,0.f,0.f}, acc_p1 = {0.f,0.f,0.f,0.f}, acc_p2 = {0.f,0.f,0.f,0.f};

    for (int kc = 0; kc < N_; kc += 16) {
        const short* Krow = Kbase + (size_t)(kc + c16)*HD_;
        const bf8v kf0 = *reinterpret_cast<const bf8v*>(Krow + g*8);
        const bf4v kf1 = *reinterpret_cast<const bf4v*>(Krow + 32 + g*4);
        const bf4v vf0 = *reinterpret_cast<const bf4v*>(Vbase + (size_t)( 0 + c16)*N_ + kc + g*4);
        const bf4v vf1 = *reinterpret_cast<const bf4v*>(Vbase + (size_t)(16 + c16)*N_ + kc + g*4);
        const bf4v vf2 = *reinterpret_cast<const bf4v*>(Vbase + (size_t)(32 + c16)*N_ + kc + g*4);

        f4v s = {0.f,0.f,0.f,0.f};
        s = __builtin_amdgcn_mfma_f32_16x16x32_bf16(kf0, qf0, s, 0, 0, 0);
        s = __builtin_amdgcn_mfma_f32_16x16x16bf16_1k(kf1, qf1, s, 0, 0, 0);

        // ---- content online softmax ----
        const float s0 = s[0]*scale, s1 = s[1]*scale, s2 = s[2]*scale, s3 = s[3]*scale;
        float cm = fmaxf(fmaxf(s0, s1), fmaxf(s2, s3));
        cm = fmaxf(cm, __shfl_xor(cm, 16));
        cm = fmaxf(cm, __shfl_xor(cm, 32));
        const bool grow_a = !__all(cm <= m_a);
        const float mna = grow_a ? fmaxf(m_a, cm) : m_a;
        const float ca  = __expf(m_a - mna);
        const float e0 = __expf(s0 - mna), e1 = __expf(s1 - mna);
        const float e2 = __expf(s2 - mna), e3 = __expf(s3 - mna);
        float zs = (e0 + e1) + (e2 + e3);
        zs += __shfl_xor(zs, 16);
        zs += __shfl_xor(zs, 32);
        z_a = z_a*ca + zs; m_a = mna;

        // ---- positional online softmax (analytic logits) ----
        const int k0 = kc + 4*g;
        float lp[4];
        #pragma unroll
        for (int i = 0; i < 4; ++i) {
            const int key = k0 + i;
            const float dx = (float)(key % 28) - nx;
            const float dy = (float)(key / 28) - ny;
            lp[i] = fmaf(w2, dx*dx + dy*dy, fmaf(w0, dx, fmaf(w1, dy, bp)));
        }
        float pm = fmaxf(fmaxf(lp[0], lp[1]), fmaxf(lp[2], lp[3]));
        pm = fmaxf(pm, __shfl_xor(pm, 16));
        pm = fmaxf(pm, __shfl_xor(pm, 32));
        const bool grow_p = !__all(pm <= m_p);
        const float mnp = grow_p ? fmaxf(m_p, pm) : m_p;
        const float cp  = __expf(m_p - mnp);
        const float p0 = __expf(lp[0]-mnp), p1 = __expf(lp[1]-mnp);
        const float p2 = __expf(lp[2]-mnp), p3 = __expf(lp[3]-mnp);
        float zps = (p0 + p1) + (p2 + p3);
        zps += __shfl_xor(zps, 16);
        zps += __shfl_xor(zps, 32);
        z_p = z_p*cp + zps; m_p = mnp;

        // ---- rescale accumulators (layout: q = 4g+i per reg) ----
        if (grow_a) {
            #pragma unroll
            for (int i = 0; i < 4; ++i) {
                const float cai = __shfl(ca, 4*g + i);
                acc_a0[i] *= cai; acc_a1[i] *= cai; acc_a2[i] *= cai;
            }
        }
        if (grow_p) {
            #pragma unroll
            for (int i = 0; i < 4; ++i) {
                const float cpi = __shfl(cp, 4*g + i);
                acc_p0[i] *= cpi; acc_p1[i] *= cpi; acc_p2[i] *= cpi;
            }
        }

        // ---- PV accumulate ----
        const bf4v pa = { f2bf(e0), f2bf(e1), f2bf(e2), f2bf(e3) };
        const bf4v pq = { f2bf(p0), f2bf(p1), f2bf(p2), f2bf(p3) };
        acc_a0 = __builtin_amdgcn_mfma_f32_16x16x16bf16_1k(pa, vf0, acc_a0, 0, 0, 0);
        acc_a1 = __builtin_amdgcn_mfma_f32_16x16x16bf16_1k(pa, vf1, acc_a1, 0, 0, 0);
        acc_a2 = __builtin_amdgcn_mfma_f32_16x16x16bf16_1k(pa, vf2, acc_a2, 0, 0, 0);
        acc_p0 = __builtin_amdgcn_mfma_f32_16x16x16bf16_1k(pq, vf0, acc_p0, 0, 0, 0);
        acc_p1 = __builtin_amdgcn_mfma_f32_16x16x16bf16_1k(pq, vf1, acc_p1, 0, 0, 0);
        acc_p2 = __builtin_amdgcn_mfma_f32_16x16x16bf16_1k(pq, vf2, acc_p2, 0, 0, 0);
    }

    // ---- final blend + store (renorm skipped: blend weights sum to 1) ----
    const float wa = (1.f - gate) / z_a;   // q = c16 layout
    const float wp = gate / z_p;
    #pragma unroll
    for (int i = 0; i < 4; ++i) {
        const float fa = __shfl(wa, 4*g + i);
        const float fp = __shfl(wp, 4*g + i);
        const int row = qt*16 + 4*g + i;
        const size_t yo = ((size_t)b*N_ + row)*D_ + h*HD_;
        Y[yo +  0 + c16] = acc_a0[i]*fa + acc_p0[i]*fp;
        Y[yo + 16 + c16] = acc_a1[i]*fa + acc_p1[i]*fp;
        Y[yo + 32 + c16] = acc_a2[i]*fa + acc_p2[i]*fp;
    }
}

// ---------------------------------------------------------------------------
// Kernel 3: output projection GEMM + bias (f32).  out = Y @ w_proj^T + b_proj
// ---------------------------------------------------------------------------
__global__ __launch_bounds__(256) void proj_gemm(
    const float* __restrict__ Yi, const float* __restrict__ w_proj,
    const float* __restrict__ b_proj, float* __restrict__ out)
{
    __shared__ float As[16][68];
    __shared__ float Bs[16][68];
    const int tid = threadIdx.x;
    const int m0 = blockIdx.x * 64;
    const int n0 = blockIdx.y * 64;
    const int lrow  = tid >> 2;
    const int lquad = (tid & 3) << 2;
    const int ty = tid >> 4, tx = tid & 15;

    float acc[4][4] = {};
    for (int k0 = 0; k0 < D_; k0 += 16) {
        float4 av = *reinterpret_cast<const float4*>(&Yi[(size_t)(m0 + lrow)*D_ + k0 + lquad]);
        float4 bv = *reinterpret_cast<const float4*>(&w_proj[(size_t)(n0 + lrow)*D_ + k0 + lquad]);
        __syncthreads();
        As[lquad+0][lrow] = av.x; As[lquad+1][lrow] = av.y;
        As[lquad+2][lrow] = av.z; As[lquad+3][lrow] = av.w;
        Bs[lquad+0][lrow] = bv.x; Bs[lquad+1][lrow] = bv.y;
        Bs[lquad+2][lrow] = bv.z; Bs[lquad+3][lrow] = bv.w;
        __syncthreads();
        #pragma unroll
        for (int k = 0; k < 16; ++k) {
            float4 a = *reinterpret_cast<const float4*>(&As[k][ty << 2]);
            float4 bq = *reinterpret_cast<const float4*>(&Bs[k][tx << 2]);
            float a4[4] = {a.x, a.y, a.z, a.w};
            float b4[4] = {bq.x, bq.y, bq.z, bq.w};
            #pragma unroll
            for (int i = 0; i < 4; ++i)
                #pragma unroll
                for (int j = 0; j < 4; ++j)
                    acc[i][j] += a4[i] * b4[j];
        }
    }

    #pragma unroll
    for (int i = 0; i < 4; ++i) {
        const int row = m0 + (ty << 2) + i;
        const int col = n0 + (tx << 2);
        float4 o;
        o.x = acc[i][0] + b_proj[col+0];
        o.y = acc[i][1] + b_proj[col+1];
        o.z = acc[i][2] + b_proj[col+2];
        o.w = acc[i][3] + b_proj[col+3];
        *reinterpret_cast<float4*>(&out[(size_t)row*D_ + col]) = o;
    }
}

// ---------------------------------------------------------------------------
extern "C" void kernel_launch(void* const* d_in, const int* in_sizes, int n_in,
                              void* d_out, int out_size, void* d_ws, size_t ws_size,
                              hipStream_t stream)
{
    const float* x      = (const float*)d_in[0];
    const float* w_qk   = (const float*)d_in[1];
    const float* w_v    = (const float*)d_in[2];
    const float* w_proj = (const float*)d_in[3];
    const float* b_proj = (const float*)d_in[4];
    const float* w_pos  = (const float*)d_in[5];
    const float* b_pos  = (const float*)d_in[6];
    const float* gating = (const float*)d_in[7];
    float* out = (float*)d_out;

    const size_t PER = (size_t)B_*H_*N_*HD_;   // 4,816,896
    short* Qb = (short*)d_ws;
    short* Kb = Qb + PER;
    short* Vt = Kb + PER;
    float* Yf = (float*)(Vt + PER);

    qkv_gemm<<<dim3(M_TOT/64, (3*D_)/64), 256, 0, stream>>>(x, w_qk, w_v, Qb, Kb, Vt);
    attn_mfma<<<dim3((B_*H_*49)/4), 256, 0, stream>>>(Qb, Kb, Vt, w_pos, b_pos, gating, Yf);
    proj_gemm<<<dim3(M_TOT/64, D_/64), 256, 0, stream>>>(Yf, w_proj, b_proj, out);
}

// Round 3
// 230.298 us; speedup vs baseline: 8.7574x; 2.3795x over previous
//
#include <hip/hip_runtime.h>
#include <hip/hip_bf16.h>
#include <cstddef>
#include <cstdint>

#define B_  8
#define N_  784
#define D_  768
#define H_  16
#define HD_ 48
#define M_TOT (B_*N_)   // 6272
#define KDIM 768
#define NQKV (3*D_)     // 2304

typedef __attribute__((ext_vector_type(8))) short bf8v;
typedef __attribute__((ext_vector_type(4))) short bf4v;
typedef __attribute__((ext_vector_type(4))) float f4v;

typedef __attribute__((address_space(3))) void lds_void;
typedef __attribute__((address_space(1))) void glb_void;

__device__ __forceinline__ short f2bf(float f) {
    __hip_bfloat16 h = __float2bfloat16(f);
    return __builtin_bit_cast(short, h);
}

__device__ __forceinline__ void gl_lds16(const short* g, short* l) {
    __builtin_amdgcn_global_load_lds((const glb_void*)g, (lds_void*)l, 16, 0, 0);
}

// ---------------------------------------------------------------------------
// Kernel 0: f32 -> bf16 conversion for x and all weight matrices.
// ---------------------------------------------------------------------------
__global__ __launch_bounds__(256) void cvt_kernel(
    const float* __restrict__ x, const float* __restrict__ wqk,
    const float* __restrict__ wv, const float* __restrict__ wpj,
    short* __restrict__ xb, short* __restrict__ wb, short* __restrict__ wpb)
{
    const int NX = M_TOT*KDIM/4;
    const int NQ = 2*D_*KDIM/4;
    const int NV = D_*KDIM/4;
    const int NP = D_*KDIM/4;
    const int tot = NX+NQ+NV+NP;
    for (int i = blockIdx.x*256 + threadIdx.x; i < tot; i += gridDim.x*256) {
        const float* s; short* d; int o = i;
        if (o < NX) { s = x; d = xb; }
        else if ((o -= NX) < NQ) { s = wqk; d = wb; }
        else if ((o -= NQ) < NV) { s = wv; d = wb + (size_t)2*D_*KDIM; }
        else { o -= NV; s = wpj; d = wpb; }
        float4 v = reinterpret_cast<const float4*>(s)[o];
        bf4v r = { f2bf(v.x), f2bf(v.y), f2bf(v.z), f2bf(v.w) };
        reinterpret_cast<bf4v*>(d)[o] = r;
    }
}

// ---------------------------------------------------------------------------
// Shared bf16 MFMA mainloop: C[128x128] tile = A[128xK] . B[128xK]^T
// LDS linear [128][64] bf16 per operand, XOR-swizzled via pre-swizzled global
// source (rule #21: swizzle BOTH global-src and ds_read, linear gload_lds dst).
// 4 waves (2x2), each 64x64 out: acc[4][4] 16x16 fragments.
// ---------------------------------------------------------------------------
__device__ __forceinline__ void mfma_mainloop(
    const short* __restrict__ A, const short* __restrict__ Bw,
    int m0, int n0, short* As, short* Bs, f4v acc[4][4])
{
    const int tid = threadIdx.x;
    const int lane = tid & 63, wid = tid >> 6;
    const int srow = lane >> 3;                 // row-within-8-row chunk
    const int scol = ((lane & 7) ^ srow) << 3;  // pre-swizzled source col (elems)
    const int c16 = lane & 15, g = lane >> 4;
    const int wm0 = (wid >> 1) * 64, wn0 = (wid & 1) * 64;

    for (int kt = 0; kt < KDIM/64; ++kt) {
        const int k0 = kt * 64;
        #pragma unroll
        for (int i = 0; i < 4; ++i) {
            const int c = i*4 + wid;            // 1KB chunk id, rows c*8..c*8+7
            gl_lds16(&A [(size_t)(m0 + c*8 + srow)*KDIM + k0 + scol], &As[c*512]);
            gl_lds16(&Bw[(size_t)(n0 + c*8 + srow)*KDIM + k0 + scol], &Bs[c*512]);
        }
        __syncthreads();
        #pragma unroll
        for (int kk = 0; kk < 2; ++kk) {
            bf8v af[4], bfr[4];
            #pragma unroll
            for (int f = 0; f < 4; ++f) {
                const int ar = wm0 + f*16 + c16;
                af[f] = *reinterpret_cast<const bf8v*>(
                    (const char*)As + ar*128 + ((kk*64 + g*16) ^ ((ar&7)<<4)));
                const int br = wn0 + f*16 + c16;
                bfr[f] = *reinterpret_cast<const bf8v*>(
                    (const char*)Bs + br*128 + ((kk*64 + g*16) ^ ((br&7)<<4)));
            }
            #pragma unroll
            for (int i = 0; i < 4; ++i)
                #pragma unroll
                for (int j = 0; j < 4; ++j)
                    acc[i][j] = __builtin_amdgcn_mfma_f32_16x16x32_bf16(af[i], bfr[j], acc[i][j], 0,0,0);
        }
        __syncthreads();
    }
}

// ---------------------------------------------------------------------------
// Kernel 1: QKV projection, bf16 MFMA.  Scatter epilogue:
//   Qb, Kb [B,H,N,48] bf16;  Vt [B,H,48,N] bf16.
// ---------------------------------------------------------------------------
__global__ __launch_bounds__(256) void qkv_mfma(
    const short* __restrict__ xb, const short* __restrict__ wb,
    short* __restrict__ Qb, short* __restrict__ Kb, short* __restrict__ Vt)
{
    __shared__ __align__(16) short As[128*64];
    __shared__ __align__(16) short Bs[128*64];
    f4v acc[4][4];
    #pragma unroll
    for (int i=0;i<4;++i)
        #pragma unroll
        for(int j=0;j<4;++j) acc[i][j] = f4v{0.f,0.f,0.f,0.f};

    const int m0 = blockIdx.x * 128, n0 = blockIdx.y * 128;
    mfma_mainloop(xb, wb, m0, n0, As, Bs, acc);

    const int lane = threadIdx.x & 63, wid = threadIdx.x >> 6;
    const int c16 = lane & 15, g = lane >> 4;
    const int wm0 = (wid>>1)*64, wn0 = (wid&1)*64;
    #pragma unroll
    for (int fr = 0; fr < 4; ++fr) {
        #pragma unroll
        for (int fc = 0; fc < 4; ++fc) {
            const int n = n0 + wn0 + fc*16 + c16;
            #pragma unroll
            for (int i = 0; i < 4; ++i) {
                const int m = m0 + wm0 + fr*16 + 4*g + i;
                const int bb = m / N_, nn = m % N_;
                const short v = f2bf(acc[fr][fc][i]);
                if (n < D_) {
                    Qb[(((size_t)bb*H_ + n/HD_)*N_ + nn)*HD_ + (n % HD_)] = v;
                } else if (n < 2*D_) {
                    const int c = n - D_;
                    Kb[(((size_t)bb*H_ + c/HD_)*N_ + nn)*HD_ + (c % HD_)] = v;
                } else {
                    const int c = n - 2*D_;
                    Vt[(((size_t)bb*H_ + c/HD_)*HD_ + (c % HD_))*N_ + nn] = v;
                }
            }
        }
    }
}

// ---------------------------------------------------------------------------
// Kernel 2: MFMA flash attention, dual online softmax (unchanged from R2
// except Y is emitted as bf16 for the MFMA proj).
// ---------------------------------------------------------------------------
__global__ __launch_bounds__(256) void attn_mfma(
    const short* __restrict__ Qb, const short* __restrict__ Kb,
    const short* __restrict__ Vt,
    const float* __restrict__ w_pos, const float* __restrict__ b_pos,
    const float* __restrict__ gating, short* __restrict__ Yb)
{
    const int lane = threadIdx.x & 63;
    const int wid  = threadIdx.x >> 6;
    const int gidx = blockIdx.x * 4 + wid;
    const int qt = gidx % 49;
    const int h  = (gidx / 49) & (H_ - 1);
    const int b  = gidx / (49 * H_);
    const int c16 = lane & 15;
    const int g   = lane >> 4;

    const size_t bh = (size_t)b*H_ + h;
    const short* Qrow  = Qb + (bh*N_ + qt*16 + c16)*HD_;
    const bf8v qf0 = *reinterpret_cast<const bf8v*>(Qrow + g*8);
    const bf4v qf1 = *reinterpret_cast<const bf4v*>(Qrow + 32 + g*4);

    const short* Kbase = Kb + bh*N_*HD_;
    const short* Vbase = Vt + bh*HD_*N_;

    const float w0 = w_pos[h*3+0], w1 = w_pos[h*3+1], w2 = w_pos[h*3+2];
    const float bp = b_pos[h];
    const float gate = 1.f / (1.f + __expf(-gating[h]));
    const float scale = 0.14433756729740643f;

    const int nq = qt*16 + c16;
    const float nx = (float)(nq % 28), ny = (float)(nq / 28);

    float m_a = -1e30f, z_a = 0.f;
    float m_p = -1e30f, z_p = 0.f;
    f4v acc_a0 = {0.f,0.f,0.f,0.f}, acc_a1 = {0.f,0.f,0.f,0.f}, acc_a2 = {0.f,0.f,0.f,0.f};
    f4v acc_p0 = {0.f,0.f,0.f,0.f}, acc_p1 = {0.f,0.f,0.f,0.f}, acc_p2 = {0.f,0.f,0.f,0.f};

    for (int kc = 0; kc < N_; kc += 16) {
        const short* Krow = Kbase + (size_t)(kc + c16)*HD_;
        const bf8v kf0 = *reinterpret_cast<const bf8v*>(Krow + g*8);
        const bf4v kf1 = *reinterpret_cast<const bf4v*>(Krow + 32 + g*4);
        const bf4v vf0 = *reinterpret_cast<const bf4v*>(Vbase + (size_t)( 0 + c16)*N_ + kc + g*4);
        const bf4v vf1 = *reinterpret_cast<const bf4v*>(Vbase + (size_t)(16 + c16)*N_ + kc + g*4);
        const bf4v vf2 = *reinterpret_cast<const bf4v*>(Vbase + (size_t)(32 + c16)*N_ + kc + g*4);

        f4v s = {0.f,0.f,0.f,0.f};
        s = __builtin_amdgcn_mfma_f32_16x16x32_bf16(kf0, qf0, s, 0, 0, 0);
        s = __builtin_amdgcn_mfma_f32_16x16x16bf16_1k(kf1, qf1, s, 0, 0, 0);

        const float s0 = s[0]*scale, s1 = s[1]*scale, s2 = s[2]*scale, s3 = s[3]*scale;
        float cm = fmaxf(fmaxf(s0, s1), fmaxf(s2, s3));
        cm = fmaxf(cm, __shfl_xor(cm, 16));
        cm = fmaxf(cm, __shfl_xor(cm, 32));
        const bool grow_a = !__all(cm <= m_a);
        const float mna = grow_a ? fmaxf(m_a, cm) : m_a;
        const float ca  = __expf(m_a - mna);
        const float e0 = __expf(s0 - mna), e1 = __expf(s1 - mna);
        const float e2 = __expf(s2 - mna), e3 = __expf(s3 - mna);
        float zs = (e0 + e1) + (e2 + e3);
        zs += __shfl_xor(zs, 16);
        zs += __shfl_xor(zs, 32);
        z_a = z_a*ca + zs; m_a = mna;

        const int k0 = kc + 4*g;
        float lp[4];
        #pragma unroll
        for (int i = 0; i < 4; ++i) {
            const int key = k0 + i;
            const float dx = (float)(key % 28) - nx;
            const float dy = (float)(key / 28) - ny;
            lp[i] = fmaf(w2, dx*dx + dy*dy, fmaf(w0, dx, fmaf(w1, dy, bp)));
        }
        float pm = fmaxf(fmaxf(lp[0], lp[1]), fmaxf(lp[2], lp[3]));
        pm = fmaxf(pm, __shfl_xor(pm, 16));
        pm = fmaxf(pm, __shfl_xor(pm, 32));
        const bool grow_p = !__all(pm <= m_p);
        const float mnp = grow_p ? fmaxf(m_p, pm) : m_p;
        const float cp  = __expf(m_p - mnp);
        const float p0 = __expf(lp[0]-mnp), p1 = __expf(lp[1]-mnp);
        const float p2 = __expf(lp[2]-mnp), p3 = __expf(lp[3]-mnp);
        float zps = (p0 + p1) + (p2 + p3);
        zps += __shfl_xor(zps, 16);
        zps += __shfl_xor(zps, 32);
        z_p = z_p*cp + zps; m_p = mnp;

        if (grow_a) {
            #pragma unroll
            for (int i = 0; i < 4; ++i) {
                const float cai = __shfl(ca, 4*g + i);
                acc_a0[i] *= cai; acc_a1[i] *= cai; acc_a2[i] *= cai;
            }
        }
        if (grow_p) {
            #pragma unroll
            for (int i = 0; i < 4; ++i) {
                const float cpi = __shfl(cp, 4*g + i);
                acc_p0[i] *= cpi; acc_p1[i] *= cpi; acc_p2[i] *= cpi;
            }
        }

        const bf4v pa = { f2bf(e0), f2bf(e1), f2bf(e2), f2bf(e3) };
        const bf4v pq = { f2bf(p0), f2bf(p1), f2bf(p2), f2bf(p3) };
        acc_a0 = __builtin_amdgcn_mfma_f32_16x16x16bf16_1k(pa, vf0, acc_a0, 0, 0, 0);
        acc_a1 = __builtin_amdgcn_mfma_f32_16x16x16bf16_1k(pa, vf1, acc_a1, 0, 0, 0);
        acc_a2 = __builtin_amdgcn_mfma_f32_16x16x16bf16_1k(pa, vf2, acc_a2, 0, 0, 0);
        acc_p0 = __builtin_amdgcn_mfma_f32_16x16x16bf16_1k(pq, vf0, acc_p0, 0, 0, 0);
        acc_p1 = __builtin_amdgcn_mfma_f32_16x16x16bf16_1k(pq, vf1, acc_p1, 0, 0, 0);
        acc_p2 = __builtin_amdgcn_mfma_f32_16x16x16bf16_1k(pq, vf2, acc_p2, 0, 0, 0);
    }

    const float wa = (1.f - gate) / z_a;
    const float wp = gate / z_p;
    #pragma unroll
    for (int i = 0; i < 4; ++i) {
        const float fa = __shfl(wa, 4*g + i);
        const float fp = __shfl(wp, 4*g + i);
        const int row = qt*16 + 4*g + i;
        const size_t yo = ((size_t)b*N_ + row)*D_ + h*HD_;
        Yb[yo +  0 + c16] = f2bf(acc_a0[i]*fa + acc_p0[i]*fp);
        Yb[yo + 16 + c16] = f2bf(acc_a1[i]*fa + acc_p1[i]*fp);
        Yb[yo + 32 + c16] = f2bf(acc_a2[i]*fa + acc_p2[i]*fp);
    }
}

// ---------------------------------------------------------------------------
// Kernel 3: output projection, bf16 MFMA + bias, f32 out.
// ---------------------------------------------------------------------------
__global__ __launch_bounds__(256) void proj_mfma(
    const short* __restrict__ Yb, const short* __restrict__ wpb,
    const float* __restrict__ b_proj, float* __restrict__ out)
{
    __shared__ __align__(16) short As[128*64];
    __shared__ __align__(16) short Bs[128*64];
    f4v acc[4][4];
    #pragma unroll
    for (int i=0;i<4;++i)
        #pragma unroll
        for(int j=0;j<4;++j) acc[i][j] = f4v{0.f,0.f,0.f,0.f};

    const int m0 = blockIdx.x * 128, n0 = blockIdx.y * 128;
    mfma_mainloop(Yb, wpb, m0, n0, As, Bs, acc);

    const int lane = threadIdx.x & 63, wid = threadIdx.x >> 6;
    const int c16 = lane & 15, g = lane >> 4;
    const int wm0 = (wid>>1)*64, wn0 = (wid&1)*64;
    #pragma unroll
    for (int fr = 0; fr < 4; ++fr) {
        #pragma unroll
        for (int fc = 0; fc < 4; ++fc) {
            const int n = n0 + wn0 + fc*16 + c16;
            const float bias = b_proj[n];
            #pragma unroll
            for (int i = 0; i < 4; ++i) {
                const int m = m0 + wm0 + fr*16 + 4*g + i;
                out[(size_t)m*D_ + n] = acc[fr][fc][i] + bias;
            }
        }
    }
}

// ---------------------------------------------------------------------------
extern "C" void kernel_launch(void* const* d_in, const int* in_sizes, int n_in,
                              void* d_out, int out_size, void* d_ws, size_t ws_size,
                              hipStream_t stream)
{
    const float* x      = (const float*)d_in[0];
    const float* w_qk   = (const float*)d_in[1];
    const float* w_v    = (const float*)d_in[2];
    const float* w_proj = (const float*)d_in[3];
    const float* b_proj = (const float*)d_in[4];
    const float* w_pos  = (const float*)d_in[5];
    const float* b_pos  = (const float*)d_in[6];
    const float* gating = (const float*)d_in[7];
    float* out = (float*)d_out;

    const size_t PER = (size_t)B_*H_*N_*HD_;      // 4,816,896
    short* xb  = (short*)d_ws;                    // M_TOT*768
    short* wb  = xb  + (size_t)M_TOT*KDIM;        // 2304*768
    short* wpb = wb  + (size_t)NQKV*KDIM;         // 768*768
    short* Qb  = wpb + (size_t)D_*KDIM;
    short* Kb  = Qb + PER;
    short* Vt  = Kb + PER;
    short* Yb  = Vt + PER;

    cvt_kernel<<<2048, 256, 0, stream>>>(x, w_qk, w_v, w_proj, xb, wb, wpb);
    qkv_mfma<<<dim3(M_TOT/128, NQKV/128), 256, 0, stream>>>(xb, wb, Qb, Kb, Vt);
    attn_mfma<<<dim3((B_*H_*49)/4), 256, 0, stream>>>(Qb, Kb, Vt, w_pos, b_pos, gating, Yb);
    proj_mfma<<<dim3(M_TOT/128, D_/128), 256, 0, stream>>>(Yb, wpb, b_proj, out);
}